// Round 2
// baseline (612.106 us; speedup 1.0000x reference)
//
#include <hip/hip_runtime.h>
#include <hip/hip_bf16.h>
#include <stdint.h>

// Problem dims (fixed by the reference)
#define E_   8
#define S_   2048
#define B_   4
#define D_   1024
#define F_   4096
#define NTOK (S_ * B_)   // 8192 tokens
#define MAXT 72          // max (expert, m-tile) entries: 8192/128 + 8

typedef __attribute__((ext_vector_type(8))) __bf16 bf16x8;
typedef __attribute__((ext_vector_type(4))) float  f32x4;

// ---- workspace layout (bytes) ----
// peak usage = 151,060,480 B (~144 MB); W2t reuses W1t's region (transposed
// after GEMM1, when W1t is dead).
#define WS_LIST 4096                       // 8192 ints (token list, grouped by expert)
#define WS_XB   65536                      // NTOK*D bf16   = 16,777,216 B
#define WS_W1T  (WS_XB + 16777216)         // E*F*D bf16    = 67,108,864 B  -> [E][F][D]
#define WS_W2T  WS_W1T                     // E*D*F bf16 (reuses W1T region) -> [E][D][F]
#define WS_H    (WS_W1T + 67108864)        // NTOK*F bf16   = 67,108,864 B
// meta ints: [0..8) counts, [8..16) base, [16] ntiles, [32..32+MAXT) tiles

__device__ __forceinline__ void gload_lds16(const void* g, void* l) {
    __builtin_amdgcn_global_load_lds(
        (const __attribute__((address_space(1))) void*)g,
        (__attribute__((address_space(3))) void*)l, 16, 0, 0);
}

// ---------------- pass 1: expert grouping ----------------
__global__ void build_lists(const int* __restrict__ mask,
                            int* __restrict__ meta, int* __restrict__ list) {
    __shared__ int cnt[E_], cur[E_];
    int tid = threadIdx.x;
    if (tid < E_) cnt[tid] = 0;
    __syncthreads();
    for (int t = tid; t < NTOK; t += 256) atomicAdd(&cnt[mask[t]], 1);
    __syncthreads();
    if (tid == 0) {
        int acc = 0, nt = 0;
        for (int e = 0; e < E_; ++e) {
            meta[e] = cnt[e];
            meta[8 + e] = acc;
            cur[e] = acc;
            acc += cnt[e];
        }
        for (int e = 0; e < E_; ++e) {
            int mt = (cnt[e] + 127) >> 7;
            for (int m = 0; m < mt; ++m) meta[32 + nt++] = (e << 16) | m;
        }
        meta[16] = nt;
        for (; nt < MAXT; ++nt) meta[32 + nt] = -1;
    }
    __syncthreads();
    for (int t = tid; t < NTOK; t += 256) {
        int e = mask[t];
        int pos = atomicAdd(&cur[e], 1);
        list[pos] = t;
    }
}

// ---------------- pass 2a: x fp32 -> bf16 ----------------
__global__ void convert_x_kernel(const float* __restrict__ x,
                                 __hip_bfloat16* __restrict__ xb) {
    size_t i = ((size_t)blockIdx.x * blockDim.x + threadIdx.x) * 4;
    const float4 v = *(const float4*)(x + i);
    union { __hip_bfloat16 h[4]; uint2 u; } o;
    o.h[0] = __float2bfloat16(v.x);
    o.h[1] = __float2bfloat16(v.y);
    o.h[2] = __float2bfloat16(v.z);
    o.h[3] = __float2bfloat16(v.w);
    *(uint2*)(xb + i) = o.u;
}

// ---------------- pass 2b: W [E][R][C] fp32 -> [E][C][R] bf16 ----------------
__global__ void transpose_convert(const float* __restrict__ src,
                                  __hip_bfloat16* __restrict__ dst,
                                  int R, int C) {
    __shared__ float tile[32][33];
    size_t off = (size_t)blockIdx.z * R * C;
    src += off; dst += off;
    int c0 = blockIdx.x * 32, r0 = blockIdx.y * 32;
    int tx = threadIdx.x & 31, ty = threadIdx.x >> 5;  // 32 x 8
#pragma unroll
    for (int i = 0; i < 4; ++i)
        tile[ty + 8 * i][tx] = src[(size_t)(r0 + ty + 8 * i) * C + c0 + tx];
    __syncthreads();
#pragma unroll
    for (int i = 0; i < 4; ++i)
        dst[(size_t)(c0 + ty + 8 * i) * R + r0 + tx] =
            __float2bfloat16(tile[tx][ty + 8 * i]);
}

// ---------------- grouped GEMM, 128x128x64 tile, 4 waves ----------------
// LAYER==1: A = xb rows gathered via list, out = relu(.+b1) -> H (bf16, grouped rows)
// LAYER==2: A = H rows (already grouped),   out = .+b2 -> scatter fp32 via list
template <int KDIM, int NDIM, int LAYER>
__global__ __launch_bounds__(256, 2) void gemm_kernel(
    const uint8_t* __restrict__ Abase,  // bf16 rows of length KDIM
    const uint8_t* __restrict__ Wt,     // bf16 [E][NDIM][KDIM] (K-contiguous)
    const float* __restrict__ bias,     // [E][NDIM]
    const int* __restrict__ meta, const int* __restrict__ list,
    __hip_bfloat16* __restrict__ Hout, float* __restrict__ Oout) {
    int te = meta[32 + blockIdx.x];
    if (te < 0) return;
    const int e = te >> 16, mt = te & 0xffff;
    const int cnt = meta[e], bse = meta[8 + e];
    const int n0 = blockIdx.y * 128;
    const int tid = threadIdx.x, wv = tid >> 6, l = tid & 63;
    const int wr = wv >> 1, wc = wv & 1;

    __shared__ __align__(16) uint8_t smem[2][32768];  // per buf: As 16KB | Bs 16KB

    const uint8_t* WtE = Wt + (size_t)e * NDIM * KDIM * 2;

    // Per-thread staging source offsets (constant over K; token gather folded in).
    size_t agoff[4], bgoff[4];
#pragma unroll
    for (int p = 0; p < 4; ++p) {
        int r = p * 32 + wv * 8 + (l >> 3);
        int grow = mt * 128 + r;
        int pidx = bse + (grow < cnt ? grow : cnt - 1);
        size_t arow = (LAYER == 1) ? (size_t)list[pidx] : (size_t)pidx;
        agoff[p] = arow * (KDIM * 2) + (size_t)(l & 7) * 16;
        bgoff[p] = (size_t)(n0 + r) * (KDIM * 2) + (size_t)(l & 7) * 16;
    }

    f32x4 acc[4][4] = {};

    auto stage = [&](int buf, int kt) {
        uint8_t* As = &smem[buf][0];
        uint8_t* Bs = &smem[buf][16384];
        size_t kb = (size_t)kt * 128;  // 64 bf16 per K-step
#pragma unroll
        for (int p = 0; p < 4; ++p) {
            gload_lds16(Abase + agoff[p] + kb, As + (p * 32 + wv * 8) * 128);
            gload_lds16(WtE + bgoff[p] + kb, Bs + (p * 32 + wv * 8) * 128);
        }
    };

    auto compute = [&](int buf) {
        const uint8_t* As = &smem[buf][0];
        const uint8_t* Bs = &smem[buf][16384];
#pragma unroll
        for (int ks = 0; ks < 2; ++ks) {
            bf16x8 a[4], b[4];
#pragma unroll
            for (int mi = 0; mi < 4; ++mi)
                a[mi] = *(const bf16x8*)(As +
                    ((wr * 64 + mi * 16 + (l & 15)) * 64 + ks * 32 + (l >> 4) * 8) * 2);
#pragma unroll
            for (int ni = 0; ni < 4; ++ni)
                b[ni] = *(const bf16x8*)(Bs +
                    ((wc * 64 + ni * 16 + (l & 15)) * 64 + ks * 32 + (l >> 4) * 8) * 2);
#pragma unroll
            for (int mi = 0; mi < 4; ++mi)
#pragma unroll
                for (int ni = 0; ni < 4; ++ni)
                    acc[mi][ni] = __builtin_amdgcn_mfma_f32_16x16x32_bf16(
                        a[mi], b[ni], acc[mi][ni], 0, 0, 0);
        }
    };

    const int KT = KDIM / 64;
    stage(0, 0);
    __syncthreads();  // drains vmcnt(0)
    int cur = 0;
    for (int kt = 0; kt < KT - 1; ++kt) {
        stage(cur ^ 1, kt + 1);  // prefetch next K-tile into other buffer
        compute(cur);
        __syncthreads();
        cur ^= 1;
    }
    compute(cur);

    // epilogue: C/D layout col = l&15, row = (l>>4)*4 + i  [m89-verified]
#pragma unroll
    for (int mi = 0; mi < 4; ++mi) {
#pragma unroll
        for (int i = 0; i < 4; ++i) {
            int rl = wr * 64 + mi * 16 + (l >> 4) * 4 + i;
            int grow = mt * 128 + rl;
            if (grow < cnt) {
#pragma unroll
                for (int ni = 0; ni < 4; ++ni) {
                    int col = n0 + wc * 64 + ni * 16 + (l & 15);
                    float v = acc[mi][ni][i] + bias[(size_t)e * NDIM + col];
                    if (LAYER == 1) {
                        v = fmaxf(v, 0.f);
                        Hout[(size_t)(bse + grow) * NDIM + col] = __float2bfloat16(v);
                    } else {
                        int tok = list[bse + grow];
                        Oout[(size_t)tok * NDIM + col] = v;
                    }
                }
            }
        }
    }
}

extern "C" void kernel_launch(void* const* d_in, const int* in_sizes, int n_in,
                              void* d_out, int out_size, void* d_ws, size_t ws_size,
                              hipStream_t stream) {
    const float* x  = (const float*)d_in[0];
    const float* W1 = (const float*)d_in[1];
    const float* b1 = (const float*)d_in[2];
    const float* W2 = (const float*)d_in[3];
    const float* b2 = (const float*)d_in[4];
    const int* mask = (const int*)d_in[5];
    float* out = (float*)d_out;

    uint8_t* ws = (uint8_t*)d_ws;
    int* meta = (int*)ws;
    int* list = (int*)(ws + WS_LIST);
    __hip_bfloat16* xb  = (__hip_bfloat16*)(ws + WS_XB);
    __hip_bfloat16* w1t = (__hip_bfloat16*)(ws + WS_W1T);
    __hip_bfloat16* w2t = (__hip_bfloat16*)(ws + WS_W2T);
    __hip_bfloat16* H   = (__hip_bfloat16*)(ws + WS_H);

    build_lists<<<1, 256, 0, stream>>>(mask, meta, list);
    convert_x_kernel<<<NTOK * D_ / 4 / 256, 256, 0, stream>>>(x, xb);
    // W1 [E][D][F] -> [E][F][D]
    transpose_convert<<<dim3(F_ / 32, D_ / 32, E_), 256, 0, stream>>>(W1, w1t, D_, F_);
    // layer 1: M=tokens, N=F, K=D
    gemm_kernel<D_, F_, 1><<<dim3(MAXT, F_ / 128), 256, 0, stream>>>(
        (const uint8_t*)xb, (const uint8_t*)w1t, b1, meta, list, H, nullptr);
    // W2 [E][F][D] -> [E][D][F]  (reuses W1t region; W1t dead after GEMM1)
    transpose_convert<<<dim3(D_ / 32, F_ / 32, E_), 256, 0, stream>>>(W2, w2t, F_, D_);
    // layer 2: M=tokens, N=D, K=F
    gemm_kernel<F_, D_, 2><<<dim3(MAXT, D_ / 128), 256, 0, stream>>>(
        (const uint8_t*)H, (const uint8_t*)w2t, b2, meta, list, nullptr, out);
}

// Round 3
// 568.044 us; speedup vs baseline: 1.0776x; 1.0776x over previous
//
#include <hip/hip_runtime.h>
#include <hip/hip_bf16.h>
#include <stdint.h>

// Problem dims (fixed by the reference)
#define E_   8
#define S_   2048
#define B_   4
#define D_   1024
#define F_   4096
#define NTOK (S_ * B_)   // 8192 tokens
#define MAXT 72          // max (expert, m-tile) entries: 8192/128 + 8

typedef __attribute__((ext_vector_type(8))) __bf16 bf16x8;
typedef __attribute__((ext_vector_type(4))) float  f32x4;

// ---- workspace layout (bytes) ----
#define WS_LIST 4096                       // 8192 ints (token list, grouped by expert)
#define WS_XB   65536                      // NTOK*D bf16   = 16,777,216 B
#define WS_W1T  (WS_XB + 16777216)         // E*F*D bf16    = 67,108,864 B  -> [E][F][D]
#define WS_W2T  WS_W1T                     // E*D*F bf16 (reuses W1T region) -> [E][D][F]
#define WS_H    (WS_W1T + 67108864)        // NTOK*F bf16   = 67,108,864 B

__device__ __forceinline__ void gload_lds16(const void* g, void* l) {
    __builtin_amdgcn_global_load_lds(
        (const __attribute__((address_space(1))) void*)g,
        (__attribute__((address_space(3))) void*)l, 16, 0, 0);
}

// ---------------- pass 1: expert grouping ----------------
__global__ void build_lists(const int* __restrict__ mask,
                            int* __restrict__ meta, int* __restrict__ list) {
    __shared__ int cnt[E_], cur[E_];
    int tid = threadIdx.x;
    if (tid < E_) cnt[tid] = 0;
    __syncthreads();
    for (int t = tid; t < NTOK; t += 256) atomicAdd(&cnt[mask[t]], 1);
    __syncthreads();
    if (tid == 0) {
        int acc = 0, nt = 0;
        for (int e = 0; e < E_; ++e) {
            meta[e] = cnt[e];
            meta[8 + e] = acc;
            cur[e] = acc;
            acc += cnt[e];
        }
        for (int e = 0; e < E_; ++e) {
            int mt = (cnt[e] + 127) >> 7;
            for (int m = 0; m < mt; ++m) meta[32 + nt++] = (e << 16) | m;
        }
        meta[16] = nt;
        for (; nt < MAXT; ++nt) meta[32 + nt] = -1;
    }
    __syncthreads();
    for (int t = tid; t < NTOK; t += 256) {
        int e = mask[t];
        int pos = atomicAdd(&cur[e], 1);
        list[pos] = t;
    }
}

// ---------------- pass 2a: x fp32 -> bf16 ----------------
__global__ void convert_x_kernel(const float* __restrict__ x,
                                 __hip_bfloat16* __restrict__ xb) {
    size_t i = ((size_t)blockIdx.x * blockDim.x + threadIdx.x) * 4;
    const float4 v = *(const float4*)(x + i);
    union { __hip_bfloat16 h[4]; uint2 u; } o;
    o.h[0] = __float2bfloat16(v.x);
    o.h[1] = __float2bfloat16(v.y);
    o.h[2] = __float2bfloat16(v.z);
    o.h[3] = __float2bfloat16(v.w);
    *(uint2*)(xb + i) = o.u;
}

// ---------------- pass 2b: W [E][R][C] fp32 -> [E][C][R] bf16 ----------------
// 128(r) x 32(c) tile; float4 reads; uint2 (4x bf16) writes -> 256B runs/32 lanes.
__global__ void transpose_convert(const float* __restrict__ src,
                                  __hip_bfloat16* __restrict__ dst,
                                  int R, int C) {
    __shared__ float tile[128][33];
    size_t off = (size_t)blockIdx.z * R * C;
    const float* s = src + off;
    __hip_bfloat16* d = dst + off;
    int r0 = blockIdx.y * 128, c0 = blockIdx.x * 32;
    int t = threadIdx.x;
    int rr = t >> 3, cc4 = (t & 7) * 4;  // 32 rows x 32 cols per pass
#pragma unroll
    for (int ii = 0; ii < 4; ++ii) {
        float4 v = *(const float4*)(s + (size_t)(r0 + rr + 32 * ii) * C + c0 + cc4);
        tile[rr + 32 * ii][cc4 + 0] = v.x;
        tile[rr + 32 * ii][cc4 + 1] = v.y;
        tile[rr + 32 * ii][cc4 + 2] = v.z;
        tile[rr + 32 * ii][cc4 + 3] = v.w;
    }
    __syncthreads();
    int wc = t >> 5;           // 8 cols per pass
    int wr = (t & 31) * 4;     // 4 consecutive rows -> one uint2
#pragma unroll
    for (int ii = 0; ii < 4; ++ii) {
        int cc = wc + 8 * ii;
        union { __hip_bfloat16 h[4]; uint2 u; } o;
#pragma unroll
        for (int k = 0; k < 4; ++k)
            o.h[k] = __float2bfloat16(tile[wr + k][cc]);
        *(uint2*)(d + (size_t)(c0 + cc) * R + r0 + wr) = o.u;
    }
}

// ---------------- grouped GEMM, 128x128x32 tile, 4 waves, dbuf 32KB ----------------
// LAYER==1: A = xb rows gathered via list, out = relu(.+b1) -> H (bf16, grouped rows)
// LAYER==2: A = H rows (already grouped),   out = .+b2 -> scatter fp32 via list
template <int KDIM, int NDIM, int LAYER>
__global__ __launch_bounds__(256, 4) void gemm_kernel(
    const uint8_t* __restrict__ Abase,  // bf16 rows of length KDIM
    const uint8_t* __restrict__ Wt,     // bf16 [E][NDIM][KDIM] (K-contiguous)
    const float* __restrict__ bias,     // [E][NDIM]
    const int* __restrict__ meta, const int* __restrict__ list,
    __hip_bfloat16* __restrict__ Hout, float* __restrict__ Oout) {
    constexpr int NT = NDIM / 128;
    // T1: bijective XCD swizzle (m204), n fastest within an XCD chunk so an
    // A-tile's 32/8 n-blocks stay on one XCD L2; same-expert tiles adjacent.
    const int nblk = MAXT * NT;
    int orig = blockIdx.x;
    int q = nblk >> 3, r = nblk & 7;
    int xcd = orig & 7, idx = orig >> 3;
    int swz = (xcd < r ? xcd * (q + 1) : r * (q + 1) + (xcd - r) * q) + idx;
    int te = meta[32 + swz / NT];
    if (te < 0) return;
    const int e = te >> 16, mt = te & 0xffff;
    const int cnt = meta[e], bse = meta[8 + e];
    const int n0 = (swz % NT) * 128;
    const int tid = threadIdx.x, wv = tid >> 6, l = tid & 63;
    const int wr = wv >> 1, wc = wv & 1;

    __shared__ __align__(16) uint8_t smem[2][16384];  // per buf: As 8KB | Bs 8KB

    const uint8_t* WtE = Wt + (size_t)e * NDIM * KDIM * 2;

    // Per-thread staging source offsets (constant over K; token gather folded in).
    // Staging row r = p*64 + wv*16 + (l>>2); lane covers bytes (l&3)*16 of the
    // 64B (32 bf16) K-slice.
    size_t agoff[2], bgoff[2];
#pragma unroll
    for (int p = 0; p < 2; ++p) {
        int rrow = p * 64 + wv * 16 + (l >> 2);
        int grow = mt * 128 + rrow;
        int pidx = bse + (grow < cnt ? grow : cnt - 1);
        size_t arow = (LAYER == 1) ? (size_t)list[pidx] : (size_t)pidx;
        agoff[p] = arow * (KDIM * 2) + (size_t)(l & 3) * 16;
        bgoff[p] = (size_t)(n0 + rrow) * (KDIM * 2) + (size_t)(l & 3) * 16;
    }

    f32x4 acc[4][4] = {};

    auto stage = [&](int buf, int kt) {
        uint8_t* As = &smem[buf][0];
        uint8_t* Bs = &smem[buf][8192];
        size_t kb = (size_t)kt * 64;  // 32 bf16 per K-step
#pragma unroll
        for (int p = 0; p < 2; ++p) {
            gload_lds16(Abase + agoff[p] + kb, As + (p * 64 + wv * 16) * 64);
            gload_lds16(WtE + bgoff[p] + kb, Bs + (p * 64 + wv * 16) * 64);
        }
    };

    auto compute = [&](int buf) {
        const uint8_t* As = &smem[buf][0];
        const uint8_t* Bs = &smem[buf][8192];
        bf16x8 a[4], b[4];
#pragma unroll
        for (int mi = 0; mi < 4; ++mi)
            a[mi] = *(const bf16x8*)(As +
                ((wr * 64 + mi * 16 + (l & 15)) * 32 + (l >> 4) * 8) * 2);
#pragma unroll
        for (int ni = 0; ni < 4; ++ni)
            b[ni] = *(const bf16x8*)(Bs +
                ((wc * 64 + ni * 16 + (l & 15)) * 32 + (l >> 4) * 8) * 2);
#pragma unroll
        for (int mi = 0; mi < 4; ++mi)
#pragma unroll
            for (int ni = 0; ni < 4; ++ni)
                acc[mi][ni] = __builtin_amdgcn_mfma_f32_16x16x32_bf16(
                    a[mi], b[ni], acc[mi][ni], 0, 0, 0);
    };

    const int KT = KDIM / 32;
    stage(0, 0);
    __syncthreads();  // drains vmcnt(0)
    int cur = 0;
    for (int kt = 0; kt < KT - 1; ++kt) {
        stage(cur ^ 1, kt + 1);  // prefetch next K-tile; latency hidden under compute
        compute(cur);
        __syncthreads();
        cur ^= 1;
    }
    compute(cur);

    // epilogue: C/D layout col = l&15, row = (l>>4)*4 + i  [m89-verified]
#pragma unroll
    for (int mi = 0; mi < 4; ++mi) {
#pragma unroll
        for (int i = 0; i < 4; ++i) {
            int rl = wr * 64 + mi * 16 + (l >> 4) * 4 + i;
            int grow = mt * 128 + rl;
            if (grow < cnt) {
#pragma unroll
                for (int ni = 0; ni < 4; ++ni) {
                    int col = n0 + wc * 64 + ni * 16 + (l & 15);
                    float v = acc[mi][ni][i] + bias[(size_t)e * NDIM + col];
                    if (LAYER == 1) {
                        v = fmaxf(v, 0.f);
                        Hout[(size_t)(bse + grow) * NDIM + col] = __float2bfloat16(v);
                    } else {
                        int tok = list[bse + grow];
                        Oout[(size_t)tok * NDIM + col] = v;
                    }
                }
            }
        }
    }
}

extern "C" void kernel_launch(void* const* d_in, const int* in_sizes, int n_in,
                              void* d_out, int out_size, void* d_ws, size_t ws_size,
                              hipStream_t stream) {
    const float* x  = (const float*)d_in[0];
    const float* W1 = (const float*)d_in[1];
    const float* b1 = (const float*)d_in[2];
    const float* W2 = (const float*)d_in[3];
    const float* b2 = (const float*)d_in[4];
    const int* mask = (const int*)d_in[5];
    float* out = (float*)d_out;

    uint8_t* ws = (uint8_t*)d_ws;
    int* meta = (int*)ws;
    int* list = (int*)(ws + WS_LIST);
    __hip_bfloat16* xb  = (__hip_bfloat16*)(ws + WS_XB);
    __hip_bfloat16* w1t = (__hip_bfloat16*)(ws + WS_W1T);
    __hip_bfloat16* w2t = (__hip_bfloat16*)(ws + WS_W2T);
    __hip_bfloat16* H   = (__hip_bfloat16*)(ws + WS_H);

    build_lists<<<1, 256, 0, stream>>>(mask, meta, list);
    convert_x_kernel<<<NTOK * D_ / 4 / 256, 256, 0, stream>>>(x, xb);
    // W1 [E][D][F] -> [E][F][D]
    transpose_convert<<<dim3(F_ / 32, D_ / 128, E_), 256, 0, stream>>>(W1, w1t, D_, F_);
    // layer 1: M=tokens, N=F, K=D
    gemm_kernel<D_, F_, 1><<<MAXT * (F_ / 128), 256, 0, stream>>>(
        (const uint8_t*)xb, (const uint8_t*)w1t, b1, meta, list, H, nullptr);
    // W2 [E][F][D] -> [E][D][F]  (reuses W1t region; W1t dead after GEMM1)
    transpose_convert<<<dim3(D_ / 32, F_ / 128, E_), 256, 0, stream>>>(W2, w2t, F_, D_);
    // layer 2: M=tokens, N=D, K=F
    gemm_kernel<F_, D_, 2><<<MAXT * (D_ / 128), 256, 0, stream>>>(
        (const uint8_t*)H, (const uint8_t*)w2t, b2, meta, list, nullptr, out);
}